// Round 10
// baseline (79.114 us; speedup 1.0000x reference)
//
#include <hip/hip_runtime.h>
#include <hip/hip_bf16.h>
#include <math.h>

#define B 256
#define S 128
#define E 768
#define E4 192      // E/4 (float4 per row)
#define NA 30
#define NNEG 10

#define K2_KC 96    // k-chunk staged in LDS
#define K2_KR 192   // k-range per block (2 chunks), ksplit = 4

__device__ __forceinline__ float dot4(float4 a, float4 b) {
    return a.x * b.x + a.y * b.y + a.z * b.z + a.w * b.w;
}
__device__ __forceinline__ float wave_reduce_sum(float v) {
#pragma unroll
    for (int off = 32; off; off >>= 1) v += __shfl_down(v, off);
    return v;   // valid on lane 0
}
__device__ __forceinline__ float wave_reduce_max(float v) {
#pragma unroll
    for (int off = 32; off; off >>= 1) v = fmaxf(v, __shfl_down(v, off));
    return v;   // valid on lane 0
}

// ---------------- K1: q-partials (2 per b, 64 rows each) + 30 prep blocks ----------------
__global__ __launch_bounds__(768) void mean_prep_kernel(const float* __restrict__ x,
                                                        const float* __restrict__ W_red,
                                                        const float* __restrict__ aspect_W,
                                                        float* __restrict__ q,      // [2][B][E]
                                                        float* __restrict__ WredT,
                                                        float* __restrict__ invn) {
    int bid = blockIdx.x;
    int tid = threadIdx.x;
    __shared__ __align__(16) float4 part[4][E4];
    __shared__ float red[12];

    if (bid < 2 * B) {
        int b = bid >> 1, half = bid & 1;
        int c = tid % E4;     // float4 column
        int g = tid / E4;     // 0..3 (s-subgroup)
        const float4* xb = (const float4*)(x + (size_t)b * S * E);
        int s0 = half * 64 + g * 16;
        float4 acc = make_float4(0.f, 0.f, 0.f, 0.f);
#pragma unroll 4
        for (int s = s0; s < s0 + 16; ++s) {
            float4 v = xb[(size_t)s * E4 + c];
            acc.x += v.x; acc.y += v.y; acc.z += v.z; acc.w += v.w;
        }
        part[g][c] = acc;
        __syncthreads();
        if (tid < E4) {
            float4 a0 = part[0][c], a1 = part[1][c], a2 = part[2][c], a3 = part[3][c];
            const float inv = 1.0f / (float)S;      // halves sum to the mean
            float4 r;
            r.x = (a0.x + a1.x + a2.x + a3.x) * inv;
            r.y = (a0.y + a1.y + a2.y + a3.y) * inv;
            r.z = (a0.z + a1.z + a2.z + a3.z) * inv;
            r.w = (a0.w + a1.w + a2.w + a3.w) * inv;
            ((float4*)q)[((size_t)half * B + b) * E4 + c] = r;
        }
    } else {
        int a = bid - 2 * B;                       // 0..29
        WredT[(size_t)a * E + tid] = W_red[(size_t)tid * NA + a];
        int wave = tid >> 6, lane = tid & 63;
        float v = aspect_W[(size_t)a * E + tid];
        float ss = wave_reduce_sum(v * v);
        if (lane == 0) red[wave] = ss;
        __syncthreads();
        if (tid == 0) {
            float n = 0.f;
#pragma unroll
            for (int w = 0; w < 12; ++w) n += red[w];
            invn[a] = 1.0f / fmaxf(sqrtf(n), 1e-12f);
        }
    }
}

// ---------------- K2: qW partials (k-split GEMM; sums the 2 q-halves in-stage) ----------------
__global__ __launch_bounds__(256) void qw_partial_kernel(const float* __restrict__ q,   // [2][B][E]
                                                         const float* __restrict__ W_att,
                                                         float* __restrict__ part) {
    int b0 = blockIdx.x * 64;
    int e0 = blockIdx.y * 64;
    int kz = blockIdx.z;
    int k0 = kz * K2_KR;
    int tid = threadIdx.x;

    __shared__ __align__(16) float qs[64][K2_KC + 4];
    __shared__ __align__(16) float ws[K2_KC][64];

    int r0 = (tid >> 3) * 2;
    int c0 = (tid & 7) * 8;

    float4 a00 = make_float4(0,0,0,0), a01 = make_float4(0,0,0,0);
    float4 a10 = make_float4(0,0,0,0), a11 = make_float4(0,0,0,0);

    for (int ch = 0; ch < 2; ++ch) {
        int kc0 = k0 + ch * K2_KC;
        {
            int row = tid >> 2, ks = (tid & 3) * 24;
            const float* src0 = q + (size_t)(b0 + row) * E + kc0 + ks;
            const float* src1 = src0 + (size_t)B * E;
#pragma unroll
            for (int j = 0; j < 6; ++j) {
                float4 v0 = *(const float4*)(src0 + 4 * j);
                float4 v1 = *(const float4*)(src1 + 4 * j);
                v0.x += v1.x; v0.y += v1.y; v0.z += v1.z; v0.w += v1.w;
                *(float4*)&qs[row][ks + 4 * j] = v0;
            }
        }
        for (int i = tid; i < K2_KC * 16; i += 256) {
            int row = i >> 4, e4 = (i & 15) * 4;
            *(float4*)&ws[row][e4] =
                *(const float4*)(W_att + (size_t)(kc0 + row) * E + e0 + e4);
        }
        __syncthreads();
#pragma unroll 4
        for (int k = 0; k < K2_KC; ++k) {
            float qa = qs[r0][k], qb = qs[r0 + 1][k];
            float4 w0 = *(const float4*)&ws[k][c0];
            float4 w1 = *(const float4*)&ws[k][c0 + 4];
            a00.x += qa * w0.x; a00.y += qa * w0.y; a00.z += qa * w0.z; a00.w += qa * w0.w;
            a01.x += qa * w1.x; a01.y += qa * w1.y; a01.z += qa * w1.z; a01.w += qa * w1.w;
            a10.x += qb * w0.x; a10.y += qb * w0.y; a10.z += qb * w0.z; a10.w += qb * w0.w;
            a11.x += qb * w1.x; a11.y += qb * w1.y; a11.z += qb * w1.z; a11.w += qb * w1.w;
        }
        __syncthreads();
    }
    float* dst = part + ((size_t)kz * B + b0 + r0) * E + e0 + c0;
    *(float4*)dst = a00; *(float4*)(dst + 4) = a01;
    *(float4*)(dst + E) = a10; *(float4*)(dst + E + 4) = a11;
}

// ---------------- K3: scores (s-half per block) + 30 ortho blocks ----------------
// grid 2*B + NA. Attn block (b,h): scores for s in [64h, 64h+64), reads x[b, that half].
__global__ __launch_bounds__(768) void score_ortho_kernel(const float* __restrict__ x,
                                                          const float* __restrict__ part,
                                                          const float* __restrict__ b_att,
                                                          const float* __restrict__ aspect_W,
                                                          const float* __restrict__ invn,
                                                          float* __restrict__ sc,
                                                          float* __restrict__ Gpart) {
    int bid = blockIdx.x;
    int tid = threadIdx.x, wave = tid >> 6, lane = tid & 63;
    __shared__ __align__(16) float4 qw4[E4];      // attn: qW[b]; ortho: normalized row i
    __shared__ float red[12];

    if (bid >= 2 * B) {
        int i = bid - 2 * B;
        float inv_i = invn[i];
        if (tid < E4) {
            float4 v = ((const float4*)aspect_W)[(size_t)i * E4 + tid];
            v.x *= inv_i; v.y *= inv_i; v.z *= inv_i; v.w *= inv_i;
            qw4[tid] = v;
        }
        __syncthreads();
        float acc = 0.f;
        for (int j = wave; j < NA; j += 12) {
            const float4* aj = (const float4*)(aspect_W + (size_t)j * E);
            float d = 0.f;
#pragma unroll
            for (int jj = 0; jj < 3; ++jj)
                d += dot4(aj[lane + 64 * jj], qw4[lane + 64 * jj]);
            d = wave_reduce_sum(d);
            if (lane == 0) {
                float g = d * invn[j] - ((i == j) ? 1.f : 0.f);
                acc += g * g;
            }
        }
        if (lane == 0) red[wave] = acc;
        __syncthreads();
        if (tid == 0) {
            float s = 0.f;
#pragma unroll
            for (int w = 0; w < 12; ++w) s += red[w];
            Gpart[i] = s;
        }
        return;
    }

    int b = bid >> 1, h = bid & 1;
    const int N4 = B * E / 4;
    // stage qW[b] = sum of 4 k-partials + b_att
    if (tid < E4) {
        const float4* p = (const float4*)part;
        size_t base = (size_t)b * E4 + tid;
        float4 s0 = p[base], s1 = p[base + N4], s2 = p[base + 2 * N4], s3 = p[base + 3 * N4];
        float4 bb = ((const float4*)b_att)[tid];
        float4 r;
        r.x = s0.x + s1.x + s2.x + s3.x + bb.x;
        r.y = s0.y + s1.y + s2.y + s3.y + bb.y;
        r.z = s0.z + s1.z + s2.z + s3.z + bb.z;
        r.w = s0.w + s1.w + s2.w + s3.w + bb.w;
        qw4[tid] = r;
    }
    __syncthreads();

    const float4* xb = (const float4*)(x + (size_t)b * S * E);
    // 32 row-pairs in this half, 2 rows per wave-iteration
    for (int p2 = wave; p2 < 32; p2 += 12) {
        int sA = h * 64 + 2 * p2;
        const float4* rA = xb + (size_t)sA * E4;
        const float4* rB = rA + E4;
        float dA = 0.f, dB = 0.f;
#pragma unroll
        for (int j = 0; j < 3; ++j) {
            float4 qv = qw4[lane + 64 * j];
            dA += dot4(rA[lane + 64 * j], qv);
            dB += dot4(rB[lane + 64 * j], qv);
        }
#pragma unroll
        for (int off = 32; off; off >>= 1) {
            dA += __shfl_down(dA, off);
            dB += __shfl_down(dB, off);
        }
        if (lane == 0) { sc[b * S + sA] = dA; sc[b * S + sA + 1] = dB; }
    }
}

// ---------------- K4: softmax (redundant, tiny) + z e-half per block ----------------
// grid 2*B. Block (b,eh): z[b, eh-half] = att . x[b,:,eh-half].
__global__ __launch_bounds__(768) void zvec_kernel(const float* __restrict__ x,
                                                   const float* __restrict__ sc,
                                                   float* __restrict__ z_s) {
    int bid = blockIdx.x;
    int b = bid >> 1, eh = bid & 1;
    int tid = threadIdx.x, wave = tid >> 6, lane = tid & 63;
    __shared__ float att[S];
    __shared__ float red[8];
    __shared__ __align__(16) float4 zpart[8][96];

    float v = (tid < S) ? sc[b * S + tid] : -3.4e38f;
    if (tid < S) {
        float m = wave_reduce_max(v);
        if (lane == 0) red[wave] = m;
    }
    __syncthreads();
    float gm = fmaxf(red[0], red[1]);
    float ex = 0.f;
    if (tid < S) {
        ex = expf(v - gm);
        float ss = wave_reduce_sum(ex);
        if (lane == 0) red[4 + wave] = ss;
    }
    __syncthreads();
    float tot = red[4] + red[5];
    if (tid < S) att[tid] = ex / tot;
    __syncthreads();

    int c = tid % 96;          // float4 col within the e-half
    int g = tid / 96;          // 0..7 (8 s-groups of 16)
    const float4* xb = (const float4*)(x + (size_t)b * S * E) + eh * 96;
    float4 acc = make_float4(0.f, 0.f, 0.f, 0.f);
#pragma unroll 4
    for (int s = g * 16; s < g * 16 + 16; ++s) {
        float w = att[s];
        float4 xv = xb[(size_t)s * E4 + c];
        acc.x += w * xv.x; acc.y += w * xv.y; acc.z += w * xv.z; acc.w += w * xv.w;
    }
    zpart[g][c] = acc;
    __syncthreads();
    if (tid < 96) {
        float4 r = make_float4(0.f, 0.f, 0.f, 0.f);
#pragma unroll
        for (int gg = 0; gg < 8; ++gg) {
            float4 a = zpart[gg][tid];
            r.x += a.x; r.y += a.y; r.z += a.z; r.w += a.w;
        }
        ((float4*)z_s)[(size_t)b * E4 + eh * 96 + tid] = r;
    }
}

// ---------------- K5: composition + reconstruction + margin (768 thr) ----------------
__global__ __launch_bounds__(768) void recon_margin_kernel(const float* __restrict__ z_s,
                                                           const float* __restrict__ WredT,
                                                           const float* __restrict__ b_red,
                                                           const float* __restrict__ aspect_W,
                                                           const int* __restrict__ neg_idx,
                                                           float* __restrict__ recon,
                                                           float* __restrict__ mpart) {
    int b = blockIdx.x;
    int tid = threadIdx.x, wave = tid >> 6, lane = tid & 63;
    __shared__ __align__(16) float4 z4[E4];
    __shared__ float comp[NA];
    __shared__ __align__(16) float r_sh[E];
    __shared__ float red[12];
    __shared__ float dots[12];

    if (tid < E4) z4[tid] = ((const float4*)(z_s + (size_t)b * E))[tid];
    __syncthreads();

    // logits over 30 aspects (12 waves)
    for (int a = wave; a < NA; a += 12) {
        const float4* wr = (const float4*)(WredT + (size_t)a * E);
        float d = 0.f;
#pragma unroll
        for (int j = 0; j < 3; ++j)
            d += dot4(wr[lane + 64 * j], z4[lane + 64 * j]);
        d = wave_reduce_sum(d);
        if (lane == 0) comp[a] = d + b_red[a];
    }
    __syncthreads();

    // softmax over 30 (wave 0)
    if (wave == 0) {
        float v = (lane < NA) ? comp[lane] : -3.4e38f;
        float m = wave_reduce_max(v);
        m = __shfl(m, 0);
        float e = (lane < NA) ? expf(v - m) : 0.f;
        float ssum = wave_reduce_sum(e);
        ssum = __shfl(ssum, 0);
        if (lane < NA) comp[lane] = e / ssum;
    }
    __syncthreads();

    // reconstruction: e = tid
    float r = 0.f;
    for (int a = 0; a < NA; ++a)
        r += comp[a] * aspect_W[(size_t)a * E + tid];
    recon[(size_t)b * E + tid] = r;
    r_sh[tid] = r;
    float sq = wave_reduce_sum(r * r);
    if (lane == 0) red[wave] = sq;
    __syncthreads();
    float tot = 0.f;
#pragma unroll
    for (int w = 0; w < 12; ++w) tot += red[w];
    float inv = 1.0f / fmaxf(sqrtf(tot), 1e-12f);

    // 11 dots: pos + 10 negatives, one per wave (waves 0..10)
    if (wave <= NNEG) {
        int row = (wave == 0) ? b : neg_idx[b * NNEG + (wave - 1)];
        const float4* zr = (const float4*)(z_s + (size_t)row * E);
        const float4* rr = (const float4*)r_sh;
        float acc = 0.f;
#pragma unroll
        for (int j = 0; j < 3; ++j)
            acc += dot4(zr[lane + 64 * j], rr[lane + 64 * j]);
        acc = wave_reduce_sum(acc);
        if (lane == 0) dots[wave] = acc;
    }
    __syncthreads();
    if (tid == 0) {
        float pos = dots[0] * inv;
        float ssum = 0.f;
        for (int n = 1; n <= NNEG; ++n)
            ssum += fmaxf(1.f - pos + dots[n] * inv, 0.f);
        mpart[b] = ssum;
    }
}

// ---------------- K6: final scalar loss ----------------
__global__ __launch_bounds__(256) void loss_kernel(const float* __restrict__ Gpart,
                                                   const float* __restrict__ mpart,
                                                   float* __restrict__ loss_out) {
    int tid = threadIdx.x, wave = tid >> 6, lane = tid & 63;
    __shared__ float ra[4], rb[4];
    float fr = (tid < NA) ? Gpart[tid] : 0.f;
    fr = wave_reduce_sum(fr);
    if (lane == 0) ra[wave] = fr;
    float mp = mpart[tid];
    mp = wave_reduce_sum(mp);
    if (lane == 0) rb[wave] = mp;
    __syncthreads();
    if (tid == 0) {
        float frob = sqrtf(ra[0] + ra[1] + ra[2] + ra[3]);
        float msum = rb[0] + rb[1] + rb[2] + rb[3];
        loss_out[0] = frob + msum * (1.0f / (float)(B * NNEG));
    }
}

extern "C" void kernel_launch(void* const* d_in, const int* in_sizes, int n_in,
                              void* d_out, int out_size, void* d_ws, size_t ws_size,
                              hipStream_t stream) {
    const float* x        = (const float*)d_in[0];
    const float* W_att    = (const float*)d_in[1];
    const float* b_att    = (const float*)d_in[2];
    const float* W_red    = (const float*)d_in[3];
    const float* b_red    = (const float*)d_in[4];
    const float* aspect_W = (const float*)d_in[5];
    const int*   neg_idx  = (const int*)d_in[6];

    float* out   = (float*)d_out;
    float* z_s   = out;                       // [B,E]
    float* recon = out + (size_t)B * E;       // [B,E]
    float* loss  = out + (size_t)2 * B * E;   // [1]

    float* ws    = (float*)d_ws;
    float* q     = ws;                        // 2*B*E (two s-half partials)
    float* part2 = q + (size_t)2 * B * E;     // 4*B*E
    float* WredT = part2 + (size_t)4 * B * E; // NA*E
    float* invn  = WredT + (size_t)NA * E;    // 32
    float* Gpart = invn + 32;                 // 32
    float* mpart = Gpart + 32;                // B
    float* sc    = mpart + B;                 // B*S

    mean_prep_kernel<<<2 * B + NA, 768, 0, stream>>>(x, W_red, aspect_W, q, WredT, invn);
    qw_partial_kernel<<<dim3(4, 12, 4), 256, 0, stream>>>(q, W_att, part2);
    score_ortho_kernel<<<2 * B + NA, 768, 0, stream>>>(x, part2, b_att, aspect_W, invn, sc, Gpart);
    zvec_kernel<<<2 * B, 768, 0, stream>>>(x, sc, z_s);
    recon_margin_kernel<<<B, 768, 0, stream>>>(z_s, WredT, b_red, aspect_W, neg_idx, recon, mpart);
    loss_kernel<<<1, 256, 0, stream>>>(Gpart, mpart, loss);
}

// Round 11
// 68.679 us; speedup vs baseline: 1.1519x; 1.1519x over previous
//
#include <hip/hip_runtime.h>
#include <hip/hip_bf16.h>
#include <hip/hip_fp16.h>
#include <math.h>

#define B 256
#define S 128
#define E 768
#define E4 192      // E/4 (float4 per row)
#define NA 30
#define NNEG 10

#define K2_KC 96    // k-chunk staged in LDS
#define K2_KR 192   // k-range per block (2 chunks), ksplit = 4

__device__ __forceinline__ float dot4(float4 a, float4 b) {
    return a.x * b.x + a.y * b.y + a.z * b.z + a.w * b.w;
}
__device__ __forceinline__ float wave_reduce_sum(float v) {
#pragma unroll
    for (int off = 32; off; off >>= 1) v += __shfl_down(v, off);
    return v;   // valid on lane 0
}
__device__ __forceinline__ float wave_reduce_max(float v) {
#pragma unroll
    for (int off = 32; off; off >>= 1) v = fmaxf(v, __shfl_down(v, off));
    return v;   // valid on lane 0
}
// convert 4 packed halfs (uint2) -> float4
__device__ __forceinline__ float4 h4_to_f4(uint2 p) {
    __half2* ph = (__half2*)&p;
    float2 f0 = __half22float2(ph[0]);
    float2 f1 = __half22float2(ph[1]);
    return make_float4(f0.x, f0.y, f1.x, f1.y);
}

// ---------------- K1: q-partials (2 per b) + optional fp16 x-copy + 30 prep blocks ----------------
template <int USE16>
__global__ __launch_bounds__(768) void mean_prep_kernel(const float* __restrict__ x,
                                                        const float* __restrict__ W_red,
                                                        const float* __restrict__ aspect_W,
                                                        float* __restrict__ q,      // [2][B][E]
                                                        float* __restrict__ WredT,
                                                        float* __restrict__ invn,
                                                        __half* __restrict__ xh) {
    int bid = blockIdx.x;
    int tid = threadIdx.x;
    __shared__ __align__(16) float4 part[4][E4];
    __shared__ float red[12];

    if (bid < 2 * B) {
        int b = bid >> 1, half = bid & 1;
        int c = tid % E4;     // float4 column
        int g = tid / E4;     // 0..3 (s-subgroup)
        const float4* xb = (const float4*)(x + (size_t)b * S * E);
        uint2* xhb = (uint2*)(xh + (size_t)b * S * E);
        int s0 = half * 64 + g * 16;
        float4 acc = make_float4(0.f, 0.f, 0.f, 0.f);
#pragma unroll 4
        for (int s = s0; s < s0 + 16; ++s) {
            float4 v = xb[(size_t)s * E4 + c];
            acc.x += v.x; acc.y += v.y; acc.z += v.z; acc.w += v.w;
            if (USE16) {
                __half2 h01 = __floats2half2_rn(v.x, v.y);
                __half2 h23 = __floats2half2_rn(v.z, v.w);
                uint2 pk;
                pk.x = *(unsigned int*)&h01;
                pk.y = *(unsigned int*)&h23;
                xhb[(size_t)s * E4 + c] = pk;
            }
        }
        part[g][c] = acc;
        __syncthreads();
        if (tid < E4) {
            float4 a0 = part[0][c], a1 = part[1][c], a2 = part[2][c], a3 = part[3][c];
            const float inv = 1.0f / (float)S;      // halves sum to the mean
            float4 r;
            r.x = (a0.x + a1.x + a2.x + a3.x) * inv;
            r.y = (a0.y + a1.y + a2.y + a3.y) * inv;
            r.z = (a0.z + a1.z + a2.z + a3.z) * inv;
            r.w = (a0.w + a1.w + a2.w + a3.w) * inv;
            ((float4*)q)[((size_t)half * B + b) * E4 + c] = r;
        }
    } else {
        int a = bid - 2 * B;                       // 0..29
        WredT[(size_t)a * E + tid] = W_red[(size_t)tid * NA + a];
        int wave = tid >> 6, lane = tid & 63;
        float v = aspect_W[(size_t)a * E + tid];
        float ss = wave_reduce_sum(v * v);
        if (lane == 0) red[wave] = ss;
        __syncthreads();
        if (tid == 0) {
            float n = 0.f;
#pragma unroll
            for (int w = 0; w < 12; ++w) n += red[w];
            invn[a] = 1.0f / fmaxf(sqrtf(n), 1e-12f);
        }
    }
}

// ---------------- K2: qW partials (k-split GEMM; sums the 2 q-halves in-stage) ----------------
__global__ __launch_bounds__(256) void qw_partial_kernel(const float* __restrict__ q,   // [2][B][E]
                                                         const float* __restrict__ W_att,
                                                         float* __restrict__ part) {
    int b0 = blockIdx.x * 64;
    int e0 = blockIdx.y * 64;
    int kz = blockIdx.z;
    int k0 = kz * K2_KR;
    int tid = threadIdx.x;

    __shared__ __align__(16) float qs[64][K2_KC + 4];
    __shared__ __align__(16) float ws[K2_KC][64];

    int r0 = (tid >> 3) * 2;
    int c0 = (tid & 7) * 8;

    float4 a00 = make_float4(0,0,0,0), a01 = make_float4(0,0,0,0);
    float4 a10 = make_float4(0,0,0,0), a11 = make_float4(0,0,0,0);

    for (int ch = 0; ch < 2; ++ch) {
        int kc0 = k0 + ch * K2_KC;
        {
            int row = tid >> 2, ks = (tid & 3) * 24;
            const float* src0 = q + (size_t)(b0 + row) * E + kc0 + ks;
            const float* src1 = src0 + (size_t)B * E;
#pragma unroll
            for (int j = 0; j < 6; ++j) {
                float4 v0 = *(const float4*)(src0 + 4 * j);
                float4 v1 = *(const float4*)(src1 + 4 * j);
                v0.x += v1.x; v0.y += v1.y; v0.z += v1.z; v0.w += v1.w;
                *(float4*)&qs[row][ks + 4 * j] = v0;
            }
        }
        for (int i = tid; i < K2_KC * 16; i += 256) {
            int row = i >> 4, e4 = (i & 15) * 4;
            *(float4*)&ws[row][e4] =
                *(const float4*)(W_att + (size_t)(kc0 + row) * E + e0 + e4);
        }
        __syncthreads();
#pragma unroll 4
        for (int k = 0; k < K2_KC; ++k) {
            float qa = qs[r0][k], qb = qs[r0 + 1][k];
            float4 w0 = *(const float4*)&ws[k][c0];
            float4 w1 = *(const float4*)&ws[k][c0 + 4];
            a00.x += qa * w0.x; a00.y += qa * w0.y; a00.z += qa * w0.z; a00.w += qa * w0.w;
            a01.x += qa * w1.x; a01.y += qa * w1.y; a01.z += qa * w1.z; a01.w += qa * w1.w;
            a10.x += qb * w0.x; a10.y += qb * w0.y; a10.z += qb * w0.z; a10.w += qb * w0.w;
            a11.x += qb * w1.x; a11.y += qb * w1.y; a11.z += qb * w1.z; a11.w += qb * w1.w;
        }
        __syncthreads();
    }
    float* dst = part + ((size_t)kz * B + b0 + r0) * E + e0 + c0;
    *(float4*)dst = a00; *(float4*)(dst + 4) = a01;
    *(float4*)(dst + E) = a10; *(float4*)(dst + E + 4) = a11;
}

// ---------------- K3: fused scores + softmax + z (two-sweep, fp16 x option) + 30 ortho blocks ----------------
template <int USE16>
__global__ __launch_bounds__(768) void attn_ortho_kernel(const float* __restrict__ x,
                                                         const __half* __restrict__ xh,
                                                         const float* __restrict__ part,
                                                         const float* __restrict__ b_att,
                                                         const float* __restrict__ aspect_W,
                                                         const float* __restrict__ invn,
                                                         float* __restrict__ z_s,
                                                         float* __restrict__ Gpart) {
    int bid = blockIdx.x;
    int tid = threadIdx.x, wave = tid >> 6, lane = tid & 63;
    __shared__ __align__(16) float4 qw4[E4];      // attn: qW[b]; ortho: normalized row i
    __shared__ float att[S];
    __shared__ float red[12];
    __shared__ __align__(16) float4 zpart[4][E4];

    if (bid >= B) {
        int i = bid - B;
        float inv_i = invn[i];
        if (tid < E4) {
            float4 v = ((const float4*)aspect_W)[(size_t)i * E4 + tid];
            v.x *= inv_i; v.y *= inv_i; v.z *= inv_i; v.w *= inv_i;
            qw4[tid] = v;
        }
        __syncthreads();
        float acc = 0.f;
        for (int j = wave; j < NA; j += 12) {
            const float4* aj = (const float4*)(aspect_W + (size_t)j * E);
            float d = 0.f;
#pragma unroll
            for (int jj = 0; jj < 3; ++jj)
                d += dot4(aj[lane + 64 * jj], qw4[lane + 64 * jj]);
            d = wave_reduce_sum(d);
            if (lane == 0) {
                float g = d * invn[j] - ((i == j) ? 1.f : 0.f);
                acc += g * g;
            }
        }
        if (lane == 0) red[wave] = acc;
        __syncthreads();
        if (tid == 0) {
            float s = 0.f;
#pragma unroll
            for (int w = 0; w < 12; ++w) s += red[w];
            Gpart[i] = s;
        }
        return;
    }

    int b = bid;
    const int N4 = B * E / 4;
    if (tid < E4) {
        const float4* p = (const float4*)part;
        size_t base = (size_t)b * E4 + tid;
        float4 s0 = p[base], s1 = p[base + N4], s2 = p[base + 2 * N4], s3 = p[base + 3 * N4];
        float4 bb = ((const float4*)b_att)[tid];
        float4 r;
        r.x = s0.x + s1.x + s2.x + s3.x + bb.x;
        r.y = s0.y + s1.y + s2.y + s3.y + bb.y;
        r.z = s0.z + s1.z + s2.z + s3.z + bb.z;
        r.w = s0.w + s1.w + s2.w + s3.w + bb.w;
        qw4[tid] = r;
    }
    __syncthreads();

    const float4* xb  = (const float4*)(x + (size_t)b * S * E);
    const uint2*  xhb = (const uint2*)(xh + (size_t)b * S * E);

    // sweep 1: scores, 2 rows per wave-iteration
    for (int p2 = wave; p2 < S / 2; p2 += 12) {
        int sA = 2 * p2;
        float dA = 0.f, dB = 0.f;
        if (USE16) {
            const uint2* rA = xhb + (size_t)sA * E4;
            const uint2* rB = rA + E4;
#pragma unroll
            for (int j = 0; j < 3; ++j) {
                float4 qv = qw4[lane + 64 * j];
                dA += dot4(h4_to_f4(rA[lane + 64 * j]), qv);
                dB += dot4(h4_to_f4(rB[lane + 64 * j]), qv);
            }
        } else {
            const float4* rA = xb + (size_t)sA * E4;
            const float4* rB = rA + E4;
#pragma unroll
            for (int j = 0; j < 3; ++j) {
                float4 qv = qw4[lane + 64 * j];
                dA += dot4(rA[lane + 64 * j], qv);
                dB += dot4(rB[lane + 64 * j], qv);
            }
        }
#pragma unroll
        for (int off = 32; off; off >>= 1) {
            dA += __shfl_down(dA, off);
            dB += __shfl_down(dB, off);
        }
        if (lane == 0) { att[sA] = dA; att[sA + 1] = dB; }
    }
    __syncthreads();

    // softmax over 128 (waves 0,1)
    float v = (tid < S) ? att[tid] : -3.4e38f;
    if (tid < S) {
        float m = wave_reduce_max(v);
        if (lane == 0) red[wave] = m;
    }
    __syncthreads();
    float gm = fmaxf(red[0], red[1]);
    float ex = 0.f;
    if (tid < S) {
        ex = expf(v - gm);
        float ss = wave_reduce_sum(ex);
        if (lane == 0) red[4 + wave] = ss;
    }
    __syncthreads();
    float tot = red[4] + red[5];
    if (tid < S) att[tid] = ex / tot;
    __syncthreads();

    // sweep 2: z[b] = att . x[b]
    int c = tid % E4, g = tid / E4;
    float4 acc = make_float4(0.f, 0.f, 0.f, 0.f);
    if (USE16) {
#pragma unroll 4
        for (int s = g * 32 + 31; s >= g * 32; --s) {
            float w = att[s];
            float4 xv = h4_to_f4(xhb[(size_t)s * E4 + c]);
            acc.x += w * xv.x; acc.y += w * xv.y; acc.z += w * xv.z; acc.w += w * xv.w;
        }
    } else {
#pragma unroll 4
        for (int s = g * 32 + 31; s >= g * 32; --s) {
            float w = att[s];
            float4 xv = xb[(size_t)s * E4 + c];
            acc.x += w * xv.x; acc.y += w * xv.y; acc.z += w * xv.z; acc.w += w * xv.w;
        }
    }
    zpart[g][c] = acc;
    __syncthreads();
    if (tid < E4) {
        float4 a0 = zpart[0][tid], a1 = zpart[1][tid], a2 = zpart[2][tid], a3 = zpart[3][tid];
        float4 r;
        r.x = a0.x + a1.x + a2.x + a3.x;
        r.y = a0.y + a1.y + a2.y + a3.y;
        r.z = a0.z + a1.z + a2.z + a3.z;
        r.w = a0.w + a1.w + a2.w + a3.w;
        ((float4*)z_s)[(size_t)b * E4 + tid] = r;
    }
}

// ---------------- K4: composition + reconstruction + margin (768 thr) ----------------
__global__ __launch_bounds__(768) void recon_margin_kernel(const float* __restrict__ z_s,
                                                           const float* __restrict__ WredT,
                                                           const float* __restrict__ b_red,
                                                           const float* __restrict__ aspect_W,
                                                           const int* __restrict__ neg_idx,
                                                           float* __restrict__ recon,
                                                           float* __restrict__ mpart) {
    int b = blockIdx.x;
    int tid = threadIdx.x, wave = tid >> 6, lane = tid & 63;
    __shared__ __align__(16) float4 z4[E4];
    __shared__ float comp[NA];
    __shared__ __align__(16) float r_sh[E];
    __shared__ float red[12];
    __shared__ float dots[12];

    if (tid < E4) z4[tid] = ((const float4*)(z_s + (size_t)b * E))[tid];
    __syncthreads();

    for (int a = wave; a < NA; a += 12) {
        const float4* wr = (const float4*)(WredT + (size_t)a * E);
        float d = 0.f;
#pragma unroll
        for (int j = 0; j < 3; ++j)
            d += dot4(wr[lane + 64 * j], z4[lane + 64 * j]);
        d = wave_reduce_sum(d);
        if (lane == 0) comp[a] = d + b_red[a];
    }
    __syncthreads();

    if (wave == 0) {
        float v = (lane < NA) ? comp[lane] : -3.4e38f;
        float m = wave_reduce_max(v);
        m = __shfl(m, 0);
        float e = (lane < NA) ? expf(v - m) : 0.f;
        float ssum = wave_reduce_sum(e);
        ssum = __shfl(ssum, 0);
        if (lane < NA) comp[lane] = e / ssum;
    }
    __syncthreads();

    float r = 0.f;
    for (int a = 0; a < NA; ++a)
        r += comp[a] * aspect_W[(size_t)a * E + tid];
    recon[(size_t)b * E + tid] = r;
    r_sh[tid] = r;
    float sq = wave_reduce_sum(r * r);
    if (lane == 0) red[wave] = sq;
    __syncthreads();
    float tot = 0.f;
#pragma unroll
    for (int w = 0; w < 12; ++w) tot += red[w];
    float inv = 1.0f / fmaxf(sqrtf(tot), 1e-12f);

    if (wave <= NNEG) {
        int row = (wave == 0) ? b : neg_idx[b * NNEG + (wave - 1)];
        const float4* zr = (const float4*)(z_s + (size_t)row * E);
        const float4* rr = (const float4*)r_sh;
        float acc = 0.f;
#pragma unroll
        for (int j = 0; j < 3; ++j)
            acc += dot4(zr[lane + 64 * j], rr[lane + 64 * j]);
        acc = wave_reduce_sum(acc);
        if (lane == 0) dots[wave] = acc;
    }
    __syncthreads();
    if (tid == 0) {
        float pos = dots[0] * inv;
        float ssum = 0.f;
        for (int n = 1; n <= NNEG; ++n)
            ssum += fmaxf(1.f - pos + dots[n] * inv, 0.f);
        mpart[b] = ssum;
    }
}

// ---------------- K5: final scalar loss ----------------
__global__ __launch_bounds__(256) void loss_kernel(const float* __restrict__ Gpart,
                                                   const float* __restrict__ mpart,
                                                   float* __restrict__ loss_out) {
    int tid = threadIdx.x, wave = tid >> 6, lane = tid & 63;
    __shared__ float ra[4], rb[4];
    float fr = (tid < NA) ? Gpart[tid] : 0.f;
    fr = wave_reduce_sum(fr);
    if (lane == 0) ra[wave] = fr;
    float mp = mpart[tid];
    mp = wave_reduce_sum(mp);
    if (lane == 0) rb[wave] = mp;
    __syncthreads();
    if (tid == 0) {
        float frob = sqrtf(ra[0] + ra[1] + ra[2] + ra[3]);
        float msum = rb[0] + rb[1] + rb[2] + rb[3];
        loss_out[0] = frob + msum * (1.0f / (float)(B * NNEG));
    }
}

extern "C" void kernel_launch(void* const* d_in, const int* in_sizes, int n_in,
                              void* d_out, int out_size, void* d_ws, size_t ws_size,
                              hipStream_t stream) {
    const float* x        = (const float*)d_in[0];
    const float* W_att    = (const float*)d_in[1];
    const float* b_att    = (const float*)d_in[2];
    const float* W_red    = (const float*)d_in[3];
    const float* b_red    = (const float*)d_in[4];
    const float* aspect_W = (const float*)d_in[5];
    const int*   neg_idx  = (const int*)d_in[6];

    float* out   = (float*)d_out;
    float* z_s   = out;                       // [B,E]
    float* recon = out + (size_t)B * E;       // [B,E]
    float* loss  = out + (size_t)2 * B * E;   // [1]

    float* ws    = (float*)d_ws;
    float* q     = ws;                        // 2*B*E
    float* part2 = q + (size_t)2 * B * E;     // 4*B*E
    float* WredT = part2 + (size_t)4 * B * E; // NA*E
    float* invn  = WredT + (size_t)NA * E;    // 32
    float* Gpart = invn + 32;                 // 32
    float* mpart = Gpart + 32;                // B
    float* endf  = mpart + B;

    size_t base_floats = (size_t)(endf - ws);
    size_t need = base_floats * sizeof(float) + (size_t)B * S * E * sizeof(__half);
    bool use16 = (ws_size >= need);
    __half* xh = (__half*)(ws + base_floats);

    if (use16) {
        mean_prep_kernel<1><<<2 * B + NA, 768, 0, stream>>>(x, W_red, aspect_W, q, WredT, invn, xh);
        qw_partial_kernel<<<dim3(4, 12, 4), 256, 0, stream>>>(q, W_att, part2);
        attn_ortho_kernel<1><<<B + NA, 768, 0, stream>>>(x, xh, part2, b_att, aspect_W, invn, z_s, Gpart);
    } else {
        mean_prep_kernel<0><<<2 * B + NA, 768, 0, stream>>>(x, W_red, aspect_W, q, WredT, invn, xh);
        qw_partial_kernel<<<dim3(4, 12, 4), 256, 0, stream>>>(q, W_att, part2);
        attn_ortho_kernel<0><<<B + NA, 768, 0, stream>>>(x, xh, part2, b_att, aspect_W, invn, z_s, Gpart);
    }
    recon_margin_kernel<<<B, 768, 0, stream>>>(z_s, WredT, b_red, aspect_W, neg_idx, recon, mpart);
    loss_kernel<<<1, 256, 0, stream>>>(Gpart, mpart, loss);
}